// Round 16
// baseline (115.642 us; speedup 1.0000x reference)
//
#include <hip/hip_runtime.h>

typedef short short8 __attribute__((ext_vector_type(8)));
typedef float floatx4 __attribute__((ext_vector_type(4)));
typedef unsigned uint2v __attribute__((ext_vector_type(2)));

#define INF 4096
#define TROWS 32
#define RS 528              // bf16 row stride: 512 B data + 16 B pad
#define TB (TROWS * RS)     // 16,896 B per buffer

// fp32 -> bf16 round-to-nearest-even (W prologue only)
__device__ __forceinline__ ushort f2bf(float f) {
  unsigned u = __builtin_bit_cast(unsigned, f);
  u += 0x7fffu + ((u >> 16) & 1u);
  return (ushort)(u >> 16);
}

// Block-diagonal GEMM v16 = v10 + double-acc, stores deferred one tile.
// v15 post-mortem: load-side deepening failed 3x -> residual is the STORE
// side. v10 hazard: STOREACC's data regs are the accs; next tile's acc
// zero-init forces a compiler vmcnt wait until all 8 stores have consumed
// their data (~vmcnt(4), half a tile after issue). At ~80% fabric util the
// 64 KB/CU/tile write stream is still queued then -> hidden store-drain per
// tile. v16: accA/accB (static names, rule #20), STOREACC(t-1) issued at the
// TOP of tile t (after LOADX so the WRITEX load-wait stays counted vmcnt(8),
// never a drain); acc regs now have a FULL tile before reuse (guard becomes
// vmcnt(16)). All waits compiler-managed (spill-robust). LDS schedule,
// W-in-regs, swapped mfma(W,x)->D[n][m], dwordx4 IO all unchanged from v10.
// Grid 256 = 16 kb x 16 mg (1024 rows = 32 tiles of 32); 512 thr, 1 WG/CU.
__global__ __launch_bounds__(512, 1) void bd_gemm(
    const float* __restrict__ x, const float* __restrict__ W,
    const float* __restrict__ bias, float* __restrict__ out)
{
  __shared__ __align__(16) char xlds[2 * TB];  // 33,792 B

  const int bid  = blockIdx.x;
  const int kb   = bid & 15;   // xcd = bid%8 -> 2 k-blocks per XCD: W L2-resident
  const int mg   = bid >> 4;   // 0..15, 1024 rows each
  const int tid  = threadIdx.x;
  const int lane = tid & 63;
  const int w    = tid >> 6;   // wave 0..7 -> out-col slice of 32
  const int ln   = lane & 15;
  const int lk   = lane >> 4;  // 0..3

  const float* xbase = x   + (size_t)(mg * 1024) * INF + kb * 256;
  float*       obase = out + (size_t)(mg * 1024) * INF + kb * 256 + w * 32;

#define LGKM0_BAR()                                                           \
  do {                                                                        \
    asm volatile("s_waitcnt lgkmcnt(0)" ::: "memory");                        \
    __builtin_amdgcn_s_barrier();                                             \
    asm volatile("" ::: "memory");                                            \
  } while (0)

  floatx4 g[4];  // staging: 4 rows/wave/tile, 16 B/lane (16 VGPR)

  // one instruction = one contiguous 1 KB fp32 row -> regs
#define LOADX(t)                                                              \
  _Pragma("unroll") for (int i_ = 0; i_ < 4; ++i_)                            \
    g[i_] = *(const floatx4*)(xbase + (size_t)((t) * TROWS + w * 4 + i_) * INF + lane * 4);

  // cvt ONCE to bf16, ds_write_b64: row r gets bytes [lane*8, lane*8+8)
#define WRITEX(t)                                                             \
  _Pragma("unroll") for (int i_ = 0; i_ < 4; ++i_) {                          \
    const int r_ = w * 4 + i_;                                                \
    unsigned p0_, p1_;                                                        \
    asm("v_cvt_pk_bf16_f32 %0, %1, %2" : "=v"(p0_) : "v"(g[i_][0]), "v"(g[i_][1])); \
    asm("v_cvt_pk_bf16_f32 %0, %1, %2" : "=v"(p1_) : "v"(g[i_][2]), "v"(g[i_][3])); \
    uint2v u_; u_[0] = p0_; u_[1] = p1_;                                      \
    *(uint2v*)(xlds + ((t) & 1) * TB + r_ * RS + lane * 8) = u_;              \
  }

  // 16 ds_read_b128 + 32 MFMA per tile per wave (frag: x[mi*16+ln][kc*32+lk*8+e])
#define COMPUTE(t, accv)                                                      \
  {                                                                           \
    const char* bb_ = xlds + ((t) & 1) * TB;                                  \
    _Pragma("unroll") for (int a_ = 0; a_ < 4; ++a_)                          \
      _Pragma("unroll") for (int e_ = 0; e_ < 4; ++e_) accv[a_][e_] = 0.0f;   \
    _Pragma("unroll") for (int kc_ = 0; kc_ < 8; ++kc_) {                     \
      short8 xf_[2];                                                          \
      _Pragma("unroll") for (int mi_ = 0; mi_ < 2; ++mi_)                     \
        xf_[mi_] = *(const short8*)(bb_ + (mi_ * 16 + ln) * RS + kc_ * 64 + lk * 16); \
      _Pragma("unroll") for (int mi_ = 0; mi_ < 2; ++mi_)                     \
        _Pragma("unroll") for (int ni_ = 0; ni_ < 2; ++ni_)                   \
          accv[mi_ * 2 + ni_] = __builtin_amdgcn_mfma_f32_16x16x32_bf16(      \
              wf[ni_][kc_], xf_[mi_], accv[mi_ * 2 + ni_], 0, 0, 0);          \
    }                                                                         \
  }

  // frag D[n][m]: m(row) = mi*16 + ln, n(col) = ni*16 + lk*4 + j -> dwordx4
#define STOREACC(t, accv)                                                     \
  _Pragma("unroll") for (int mi_ = 0; mi_ < 2; ++mi_)                         \
    _Pragma("unroll") for (int ni_ = 0; ni_ < 2; ++ni_) {                     \
      floatx4 r_ = accv[mi_ * 2 + ni_];                                       \
      _Pragma("unroll") for (int j_ = 0; j_ < 4; ++j_) r_[j_] += bv[ni_][j_]; \
      *(floatx4*)(obase + (size_t)((t) * TROWS + mi_ * 16 + ln) * INF +       \
                  ni_ * 16 + lk * 4) = r_;                                    \
    }

  // ---- prologue: tile-0 loads first, W frags under their latency ----
  LOADX(0)

  short8 wf[2][8];  // wave w cols [w*32, w*32+32): A-layout [row=n (ln)][k=lk*8+e]
  {
    const float* wp = W + (size_t)kb * 65536 + (w * 32 + ln) * 256 + lk * 8;
#pragma unroll
    for (int ni = 0; ni < 2; ++ni)
#pragma unroll
      for (int kc = 0; kc < 8; ++kc) {
        const float* s = wp + ni * 16 * 256 + kc * 32;
        floatx4 v0 = *(const floatx4*)s;
        floatx4 v1 = *(const floatx4*)(s + 4);
        short8 u;
#pragma unroll
        for (int j = 0; j < 4; ++j) {
          u[j]     = (short)f2bf(v0[j]);
          u[4 + j] = (short)f2bf(v1[j]);
        }
        wf[ni][kc] = u;
      }
  }
  floatx4 bv[2];
#pragma unroll
  for (int ni = 0; ni < 2; ++ni)
    bv[ni] = *(const floatx4*)(bias + kb * 256 + w * 32 + ni * 16 + lk * 4);

  floatx4 accA[4], accB[4];  // static double accumulator (rule #20)

  WRITEX(0)        // compiler's vmcnt wait for g sits here (after W prologue)
  LGKM0_BAR();

  // ---- main loop: 16 pairs = 32 tiles; stores deferred one full tile ----
  // per tile body: LOADX(t+1) [loads FIRST so WRITEX's wait stays vmcnt(8)];
  // STOREACC(t-1) [data regs free one full tile before reuse]; COMPUTE(t);
  // WRITEX(t+1); BAR. accA = even tiles, accB = odd.
#pragma unroll 1
  for (int p = 0; p < 16; ++p) {
    const int t0 = 2 * p, t1 = 2 * p + 1;
    // tile t0 (even -> accA; stores tile t0-1 from accB)
    if (t0 < 31) LOADX(t0 + 1)
    if (p > 0)   STOREACC(t0 - 1, accB)
    COMPUTE(t0, accA)
    if (t0 < 31) {
      WRITEX(t0 + 1)
      LGKM0_BAR();
    }
    // tile t1 (odd -> accB; stores tile t0 from accA)
    if (t1 < 31) LOADX(t1 + 1)
    STOREACC(t0, accA)
    COMPUTE(t1, accB)
    if (t1 < 31) {
      WRITEX(t1 + 1)
      LGKM0_BAR();
    }
  }
  STOREACC(31, accB)

#undef LGKM0_BAR
#undef LOADX
#undef WRITEX
#undef COMPUTE
#undef STOREACC
}

extern "C" void kernel_launch(void* const* d_in, const int* in_sizes, int n_in,
                              void* d_out, int out_size, void* d_ws, size_t ws_size,
                              hipStream_t stream) {
  const float* x = (const float*)d_in[0];
  const float* W = (const float*)d_in[1];
  const float* b = (const float*)d_in[2];
  float* out = (float*)d_out;
  // 16 k-blocks x 16 m-groups = 256 WGs (1/CU), 512 threads (8 waves)
  hipLaunchKernelGGL(bd_gemm, dim3(256), dim3(512), 0, stream, x, W, b, out);
}